// Round 2
// baseline (596.779 us; speedup 1.0000x reference)
//
#include <hip/hip_runtime.h>
#include <math.h>

#define CRF_B 256
#define CRF_S 2048
#define CRF_K 64

typedef float v2f __attribute__((ext_vector_type(2)));
typedef float v4f __attribute__((ext_vector_type(4)));

// ws layout (floats):
//   pf   [B*K]   forward  p at the meet point (uniform scale, folded into Cf)
//   Cf   [B]
//   pb   [B*K]   backward p at the meet point
//   Cb   [B]
//   gold [B]     emission+transition sums
__device__ __forceinline__ float waveMax(float v) {
#pragma unroll
    for (int k = 32; k >= 1; k >>= 1)
        v = fmaxf(v, __shfl_xor(v, k, 64));
    return v;
}

// Compiler-only fence. Blocks are a single wave: DS ops from one wave are
// processed in-order by the LDS pipe, so cross-lane write->read visibility
// needs no s_barrier (verified round 1: absmax 0 with this scheme).
__device__ __forceinline__ void lds_fence() { asm volatile("" ::: "memory"); }

// Per-step normalization: strip lane-0's power-of-two exponent (uniform across
// the wave). q > 0 always (sums of positive terms), so the bit-extract is valid.
__device__ __forceinline__ float stripExp(float q, int& eAcc) {
    const int u = __builtin_amdgcn_readfirstlane(__float_as_int(q));
    const int e = ((u >> 23) & 0xff) - 126;   // 2^-e * q0 in [0.5, 1)
    eAcc += e;
    return ldexpf(q, -e);
}

__global__ __launch_bounds__(64) void crf_scan_kernel(
    const float* __restrict__ scores, const float* __restrict__ trans,
    const float* __restrict__ source, const float* __restrict__ sink,
    float* __restrict__ ws)
{
    const int lane = threadIdx.x;
    const bool fwd = blockIdx.x < 128;
    const int pairIdx = fwd ? blockIdx.x : (blockIdx.x - 128);
    const int b0 = 2 * pairIdx;
    const int b1 = b0 + 1;

    __shared__ __align__(16) v4f shv[2][2][CRF_K / 4];  // [stream][parity][16 x float4]

    // E in v2f pairs: fwd lane holds column `lane` of exp(T) (pairs over rows i);
    // bwd lane holds row `lane` (pairs over cols j). Shared by both streams.
    v2f E2[CRF_K / 2];
    if (fwd) {
#pragma unroll
        for (int m = 0; m < CRF_K / 2; ++m) {
            v2f e;
            e.x = __expf(trans[(2 * m + 0) * CRF_K + lane]);
            e.y = __expf(trans[(2 * m + 1) * CRF_K + lane]);
            E2[m] = e;
        }
    } else {
        const float4* row = (const float4*)(trans + lane * CRF_K);
#pragma unroll
        for (int jj = 0; jj < CRF_K / 4; ++jj) {
            float4 t4 = row[jj];
            v2f e0, e1;
            e0.x = __expf(t4.x); e0.y = __expf(t4.y);
            e1.x = __expf(t4.z); e1.y = __expf(t4.w);
            E2[2 * jj + 0] = e0;
            E2[2 * jj + 1] = e1;
        }
    }

    const float* scA = scores + (size_t)b0 * CRF_S * CRF_K + lane;
    const float* scB = scores + (size_t)b1 * CRF_S * CRF_K + lane;

    float pA, pB, CA, CB;
    int eiA = 0, eiB = 0;
    float bufA[8], bufB[8];  // software prefetch, depth 8, per stream

    // Interleaved dual dot: qS = sum_i sh[S][par][i] * E2[i]. The interleave of
    // A/B streams hides each stream's LDS roundtrip behind the other's issue.
    auto dot2 = [&](int par, float& qA, float& qB) {
        const v4f* shA = shv[0][par];
        const v4f* shB = shv[1][par];
        v2f aA0 = {0.f, 0.f}, aA1 = aA0, aA2 = aA0, aA3 = aA0;
        v2f aB0 = aA0, aB1 = aA0, aB2 = aA0, aB3 = aA0;
#pragma unroll
        for (int i = 0; i < CRF_K / 4; i += 2) {
            const v4f va0 = shA[i], va1 = shA[i + 1];
            const v4f vb0 = shB[i], vb1 = shB[i + 1];
            aA0 = __builtin_elementwise_fma(__builtin_shufflevector(va0, va0, 0, 1), E2[2 * i + 0], aA0);
            aA1 = __builtin_elementwise_fma(__builtin_shufflevector(va0, va0, 2, 3), E2[2 * i + 1], aA1);
            aA2 = __builtin_elementwise_fma(__builtin_shufflevector(va1, va1, 0, 1), E2[2 * i + 2], aA2);
            aA3 = __builtin_elementwise_fma(__builtin_shufflevector(va1, va1, 2, 3), E2[2 * i + 3], aA3);
            aB0 = __builtin_elementwise_fma(__builtin_shufflevector(vb0, vb0, 0, 1), E2[2 * i + 0], aB0);
            aB1 = __builtin_elementwise_fma(__builtin_shufflevector(vb0, vb0, 2, 3), E2[2 * i + 1], aB1);
            aB2 = __builtin_elementwise_fma(__builtin_shufflevector(vb1, vb1, 0, 1), E2[2 * i + 2], aB2);
            aB3 = __builtin_elementwise_fma(__builtin_shufflevector(vb1, vb1, 2, 3), E2[2 * i + 3], aB3);
        }
        const v2f rA = (aA0 + aA1) + (aA2 + aA3);
        const v2f rB = (aB0 + aB1) + (aB2 + aB3);
        qA = rA.x + rA.y;
        qB = rB.x + rB.y;
    };

    if (fwd) {
        const float a0A = source[lane] + scA[0];
        const float a0B = source[lane] + scB[0];
        CA = waveMax(a0A); pA = __expf(a0A - CA);
        CB = waveMax(a0B); pB = __expf(a0B - CB);
#pragma unroll
        for (int k = 0; k < 8; ++k) { bufA[k] = scA[(1 + k) * CRF_K]; bufB[k] = scB[(1 + k) * CRF_K]; }
        for (int g = 0; g < 128; ++g) {
            const int tbase = 1 + g * 8;
#pragma unroll
            for (int k = 0; k < 8; ++k) {
                const float sA = bufA[k];
                const float sB = bufB[k];
                // prefetch 8 ahead; max index 1032 < 2048 (in-bounds, maybe unused)
                bufA[k] = scA[(tbase + 8 + k) * CRF_K];
                bufB[k] = scB[(tbase + 8 + k) * CRF_K];
                ((float*)shv[0][k & 1])[lane] = pA;
                ((float*)shv[1][k & 1])[lane] = pB;
                lds_fence();
                float qA, qB;
                dot2(k & 1, qA, qB);
                lds_fence();
                pA = stripExp(qA, eiA) * __expf(sA);
                pB = stripExp(qB, eiB) * __expf(sB);
            }
        }
    } else {
        const float bA = sink[lane];
        CA = waveMax(bA); pA = __expf(bA - CA);
        CB = CA; pB = pA;  // sink identical for both chains
#pragma unroll
        for (int k = 0; k < 8; ++k) { bufA[k] = scA[(2047 - k) * CRF_K]; bufB[k] = scB[(2047 - k) * CRF_K]; }
        for (int g = 0; g < 127; ++g) {
            const int nbase = g * 8;
#pragma unroll
            for (int k = 0; k < 8; ++k) {
                const float sA = bufA[k];
                const float sB = bufB[k];
                // prefetch; min index 2047-1023 = 1024 >= 0
                bufA[k] = scA[(2047 - (nbase + 8 + k)) * CRF_K];
                bufB[k] = scB[(2047 - (nbase + 8 + k)) * CRF_K];
                ((float*)shv[0][k & 1])[lane] = pA * __expf(sA);
                ((float*)shv[1][k & 1])[lane] = pB * __expf(sB);
                lds_fence();
                float qA, qB;
                dot2(k & 1, qA, qB);
                lds_fence();
                pA = stripExp(qA, eiA);
                pB = stripExp(qB, eiB);
            }
        }
        // epilogue: 7 steps, buf[0..6] already prefetched (indices 1031..1025)
#pragma unroll
        for (int k = 0; k < 7; ++k) {
            const float sA = bufA[k];
            const float sB = bufB[k];
            ((float*)shv[0][k & 1])[lane] = pA * __expf(sA);
            ((float*)shv[1][k & 1])[lane] = pB * __expf(sB);
            lds_fence();
            float qA, qB;
            dot2(k & 1, qA, qB);
            lds_fence();
            pA = stripExp(qA, eiA);
            pB = stripExp(qB, eiB);
        }
    }

    float* pf = ws;
    float* Cf = ws + CRF_B * CRF_K;
    float* pb = Cf + CRF_B;
    float* Cb = pb + CRF_B * CRF_K;
    const float LN2 = 0.6931471805599453f;
    if (fwd) {
        pf[b0 * CRF_K + lane] = pA;
        pf[b1 * CRF_K + lane] = pB;
        if (lane == 0) { Cf[b0] = CA + (float)eiA * LN2; Cf[b1] = CB + (float)eiB * LN2; }
    } else {
        pb[b0 * CRF_K + lane] = pA;
        pb[b1 * CRF_K + lane] = pB;
        if (lane == 0) { Cb[b0] = CA + (float)eiA * LN2; Cb[b1] = CB + (float)eiB * LN2; }
    }
}

__global__ __launch_bounds__(1024) void crf_gold_kernel(
    const float* __restrict__ scores, const int* __restrict__ states,
    const float* __restrict__ trans, const float* __restrict__ source,
    const float* __restrict__ sink, float* __restrict__ gold)
{
    const int b = blockIdx.x;
    const int tid = threadIdx.x;
    const int* st = states + (size_t)b * CRF_S;

    float g = 0.f;
#pragma unroll
    for (int t = tid; t < CRF_S; t += 1024) {
        const int cur = st[t];
        g += scores[((size_t)b * CRF_S + t) * CRF_K + cur];
        if (t > 0) g += trans[st[t - 1] * CRF_K + cur];
    }
#pragma unroll
    for (int k = 32; k >= 1; k >>= 1) g += __shfl_xor(g, k, 64);

    __shared__ float wsum[16];
    if ((tid & 63) == 0) wsum[tid >> 6] = g;
    __syncthreads();
    if (tid < 64) {
        float v = (tid < 16) ? wsum[tid] : 0.f;
#pragma unroll
        for (int k = 8; k >= 1; k >>= 1) v += __shfl_xor(v, k, 64);
        if (tid == 0) gold[b] = source[st[0]] + sink[st[CRF_S - 1]] + v;
    }
}

__global__ __launch_bounds__(256) void crf_finish_kernel(
    const float* __restrict__ ws, float* __restrict__ out)
{
    const int b = threadIdx.x;  // one thread per batch element
    const float* pf = ws;
    const float* Cf = ws + CRF_B * CRF_K;
    const float* pb = Cf + CRF_B;
    const float* Cb = pb + CRF_B * CRF_K;
    const float* gold = Cb + CRF_B;

    const float4* pf4 = (const float4*)(pf + b * CRF_K);
    const float4* pb4 = (const float4*)(pb + b * CRF_K);
    float sum = 0.f;
#pragma unroll
    for (int j = 0; j < CRF_K / 4; ++j) {
        const float4 a = pf4[j];
        const float4 c = pb4[j];
        sum += a.x * c.x + a.y * c.y + a.z * c.z + a.w * c.w;
    }
    float loss = Cf[b] + Cb[b] + logf(sum) - gold[b];

    __shared__ float red[256];
    red[b] = loss;
    __syncthreads();
    for (int s2 = 128; s2 > 0; s2 >>= 1) {
        if (b < s2) red[b] += red[b + s2];
        __syncthreads();
    }
    if (b == 0) out[0] = red[0] * (1.0f / CRF_B);
}

extern "C" void kernel_launch(void* const* d_in, const int* in_sizes, int n_in,
                              void* d_out, int out_size, void* d_ws, size_t ws_size,
                              hipStream_t stream) {
    const float* scores = (const float*)d_in[0];
    const int*   states = (const int*)d_in[1];
    const float* trans  = (const float*)d_in[2];
    const float* source = (const float*)d_in[3];
    const float* sink   = (const float*)d_in[4];

    float* ws = (float*)d_ws;
    float* gold = ws + 2 * (CRF_B * CRF_K + CRF_B);
    float* out = (float*)d_out;

    crf_scan_kernel<<<CRF_B, CRF_K, 0, stream>>>(scores, trans, source, sink, ws);
    crf_gold_kernel<<<CRF_B, 1024, 0, stream>>>(scores, states, trans, source, sink, gold);
    crf_finish_kernel<<<1, 256, 0, stream>>>(ws, out);
}

// Round 3
// 280.918 us; speedup vs baseline: 2.1244x; 2.1244x over previous
//
#include <hip/hip_runtime.h>
#include <hip/hip_bf16.h>
#include <math.h>

#define CRF_B 256
#define CRF_S 2048
#define CRF_K 64
#define NSEG 16
#define SEGL 128
#define BURN 64
#define DEPTH 192  // BURN + SEGL

typedef short bf16x8 __attribute__((ext_vector_type(8)));  // 8 bf16 = 4 VGPRs
typedef float f32x4 __attribute__((ext_vector_type(4)));

// ws layout (floats): c[B][NSEG], vlast[B][K], gold[B]

// Compiler-only fence; block = 1 wave, DS pipe is in-order per wave
// (write->read visibility verified rounds 1-2, absmax 0).
__device__ __forceinline__ void lds_fence() { asm volatile("" ::: "memory"); }

__device__ __forceinline__ unsigned bf16rne(float x) {
    unsigned u = __float_as_uint(x);
    return (u + 0x7FFFu + ((u >> 16) & 1u)) >> 16;
}
__device__ __forceinline__ unsigned pkbf(float a, float b) {
    return bf16rne(a) | (bf16rne(b) << 16);
}

// One wave per batch b. 16 chains = 16 segments of b's sequence, chain id = lane&15.
// Chain s: steps k=0..191 process t = s*128 - 63 + k (clamped to [1,2047]);
// k<64 = burn-in from uniform (direction convergence), k>=64 = accumulation of
// exact power-of-two strip bookkeeping. Seg 0 gets its exact init at k=63;
// seg 15's step at k=191 (t=2048) is masked out (frozen).
// MFMA (transposed form): D[state][chain] = sum_i E[i][state] * P[chain][i],
//   A (static) = E-fragments, B = P from LDS, per verified gfx950 layouts:
//   A[m=lane&15][k=(lane>>4)*8+j], C[row=(lane>>4)*4+reg][col=lane&15].
__global__ __launch_bounds__(64) void crf_scan(
    const float* __restrict__ scores, const int* __restrict__ states,
    const float* __restrict__ trans, const float* __restrict__ source,
    const float* __restrict__ sink, float* __restrict__ ws)
{
    const int lane = threadIdx.x;
    const int b = blockIdx.x;
    const int c = lane & 15;  // chain / segment id
    const int q = lane >> 4;  // quad

    float* wsC = ws;                   // [B][NSEG]
    float* wsV = ws + CRF_B * NSEG;    // [B][K]
    float* wsG = wsV + CRF_B * CRF_K;  // [B]

    __shared__ __align__(16) short Pbuf[16 * 72];  // [chain][state], stride 72 bf16 (16B-aligned rows)

    // ---------- fused gold-path partial (independent of scan; overlaps setup) ----------
    {
        const int* st = states + b * CRF_S;
        const float* scb = scores + (size_t)b * CRF_S * CRF_K;
        float g = 0.f;
#pragma unroll 4
        for (int it = 0; it < 32; ++it) {
            int p = it * 64 + lane;
            int cur = st[p];
            g += scb[(size_t)p * CRF_K + cur];
            if (p > 0) g += trans[st[p - 1] * CRF_K + cur];
        }
        if (lane == 0) g += source[st[0]];
        if (lane == 63) g += sink[st[CRF_S - 1]];
#pragma unroll
        for (int m = 32; m >= 1; m >>= 1) g += __shfl_xor(g, m, 64);
        if (lane == 0) wsG[b] = g;
    }

    // ---------- static E fragments (A operand), bf16 ----------
    // A_{g,h}[jj=c][kk=q*8+jv] = exp(trans[h*32+q*8+jv][g*16+c])
    bf16x8 Af[4][2];
#pragma unroll
    for (int g4 = 0; g4 < 4; ++g4)
#pragma unroll
        for (int h = 0; h < 2; ++h) {
            bf16x8 t;
#pragma unroll
            for (int jv = 0; jv < 8; ++jv) {
                int row = h * 32 + q * 8 + jv;
                int col = g4 * 16 + c;
                t[jv] = (short)bf16rne(__expf(trans[row * CRF_K + col]));
            }
            Af[g4][h] = t;
        }

    // exact init for chain 0: exp(source + scores[b][0][:])
    float ini[16];
#pragma unroll
    for (int g4 = 0; g4 < 4; ++g4)
#pragma unroll
        for (int r = 0; r < 4; ++r) {
            int st8 = 16 * g4 + 4 * q + r;
            ini[g4 * 4 + r] = __expf(source[st8] + scores[(size_t)b * CRF_S * CRF_K + st8]);
        }

    // P init: uniform ones
    {
        unsigned one2 = pkbf(1.f, 1.f);
#pragma unroll
        for (int g4 = 0; g4 < 4; ++g4)
            *(int2*)(Pbuf + c * 72 + 16 * g4 + 4 * q) = make_int2((int)one2, (int)one2);
    }
    lds_fence();
    bf16x8 bf0 = *(const bf16x8*)(Pbuf + c * 72 + q * 8);
    bf16x8 bf1 = *(const bf16x8*)(Pbuf + c * 72 + 32 + q * 8);

    // emission prefetch pipeline, distance 4 (covers HBM latency)
    const float* scq = scores + (size_t)b * CRF_S * CRF_K + 4 * q;
    float raw[4][16];
#pragma unroll
    for (int ph = 0; ph < 4; ++ph) {
        int t = c * SEGL - (BURN - 1) + ph;
        t = min(max(t, 1), CRF_S - 1);
        const float* pr = scq + (size_t)t * CRF_K;
#pragma unroll
        for (int g4 = 0; g4 < 4; ++g4)
#pragma unroll
            for (int r = 0; r < 4; ++r)
                raw[ph][g4 * 4 + r] = pr[16 * g4 + r];
    }
    float esb[2][16];
#pragma unroll
    for (int i = 0; i < 16; ++i) esb[0][i] = __expf(raw[0][i]);

    int e_stale = 0;  // power-of-two strip applied this step (stale by 1, exact bookkeeping)
    int cint = 0;     // accumulated strip exponents (counted from k>=BURN)
    float v[16];
    float vkeep[16];
#pragma unroll
    for (int i = 0; i < 16; ++i) { v[i] = 1.f; vkeep[i] = 0.f; }

    for (int kk = 0; kk < DEPTH; kk += 4) {
#pragma unroll
        for (int ph = 0; ph < 4; ++ph) {
            const int k = kk + ph;
            // (1) exp for step k+1 (raw slot (k+1)&3, loaded 3 steps ago)
            {
                const int ebn = (ph + 1) & 1;
#pragma unroll
                for (int i = 0; i < 16; ++i) esb[ebn][i] = __expf(raw[(ph + 1) & 3][i]);
            }
            // (2) MFMA: D[state][chain], 4 col-groups x 2 K-halves
            f32x4 acc[4];
#pragma unroll
            for (int g4 = 0; g4 < 4; ++g4) {
                f32x4 z = {0.f, 0.f, 0.f, 0.f};
                z = __builtin_amdgcn_mfma_f32_16x16x32_bf16(Af[g4][0], bf0, z, 0, 0, 0);
                z = __builtin_amdgcn_mfma_f32_16x16x32_bf16(Af[g4][1], bf1, z, 0, 0, 0);
                acc[g4] = z;
            }
            // (3) emission multiply + stale strip
            const float s2 = ldexpf(1.0f, -e_stale);
            if (k >= BURN) cint += e_stale;
#pragma unroll
            for (int g4 = 0; g4 < 4; ++g4)
#pragma unroll
                for (int r = 0; r < 4; ++r)
                    v[g4 * 4 + r] = acc[g4][r] * esb[ph & 1][g4 * 4 + r] * s2;

            if (k == DEPTH - 2) {
#pragma unroll
                for (int i = 0; i < 16; ++i) vkeep[i] = v[i];
            }
            if (k == DEPTH - 1) {  // chain 15's t=2048 step doesn't exist: freeze (strip still applied)
#pragma unroll
                for (int i = 0; i < 16; ++i) v[i] = (c == 15) ? vkeep[i] * s2 : v[i];
            }
            // (4) next stale exponent: per-chain max (own chain in this lane + 2 shfls across quads)
            float mx = v[0];
#pragma unroll
            for (int i = 1; i < 16; ++i) mx = fmaxf(mx, v[i]);
            mx = fmaxf(mx, __shfl_xor(mx, 16, 64));
            mx = fmaxf(mx, __shfl_xor(mx, 32, 64));
            int eN = ((__float_as_int(mx) >> 23) & 255) - 126;
            // (5) burn-in -> accumulation boundary: chain-0 init + canonical strip
            if (k == BURN - 1) {
#pragma unroll
                for (int i = 0; i < 16; ++i) v[i] = (c == 0) ? ini[i] : v[i];
                float mc = v[0];
#pragma unroll
                for (int i = 1; i < 16; ++i) mc = fmaxf(mc, v[i]);
                mc = fmaxf(mc, __shfl_xor(mc, 16, 64));
                mc = fmaxf(mc, __shfl_xor(mc, 32, 64));
                int ec = ((__float_as_int(mc) >> 23) & 255) - 126;
                const float sc2 = ldexpf(1.0f, -ec);
#pragma unroll
                for (int i = 0; i < 16; ++i) v[i] *= sc2;
                cint = (c == 0) ? ec : 0;  // seg 0 carries alpha_0's exact scale; others start at 0
                e_stale = 0;
            } else {
                e_stale = eN;
            }
            // (6) convert + write own chain's 16 states (4 x ds_write_b64)
#pragma unroll
            for (int g4 = 0; g4 < 4; ++g4) {
                unsigned lo = pkbf(v[g4 * 4 + 0], v[g4 * 4 + 1]);
                unsigned hi = pkbf(v[g4 * 4 + 2], v[g4 * 4 + 3]);
                *(int2*)(Pbuf + c * 72 + 16 * g4 + 4 * q) = make_int2((int)lo, (int)hi);
            }
            lds_fence();
            // (7) B fragments for step k+1 (2 x ds_read_b128)
            bf0 = *(const bf16x8*)(Pbuf + c * 72 + q * 8);
            bf1 = *(const bf16x8*)(Pbuf + c * 72 + 32 + q * 8);
            // (8) issue emission loads for step k+4
            {
                int t = c * SEGL - (BURN - 1) + k + 4;
                t = min(max(t, 1), CRF_S - 1);
                const float* pr = scq + (size_t)t * CRF_K;
#pragma unroll
                for (int g4 = 0; g4 < 4; ++g4)
#pragma unroll
                    for (int r = 0; r < 4; ++r)
                        raw[ph][g4 * 4 + r] = pr[16 * g4 + r];
            }
        }
    }

    // final canonical strip (handoff-consistent with next segment's burn-in canonical)
    float mf = v[0];
#pragma unroll
    for (int i = 1; i < 16; ++i) mf = fmaxf(mf, v[i]);
    mf = fmaxf(mf, __shfl_xor(mf, 16, 64));
    mf = fmaxf(mf, __shfl_xor(mf, 32, 64));
    int ef = ((__float_as_int(mf) >> 23) & 255) - 126;
    cint += ef;
    const float sf = ldexpf(1.0f, -ef);

    if (q == 0) wsC[b * NSEG + c] = (float)cint * 0.6931471805599453f;
    if (c == 15) {
#pragma unroll
        for (int g4 = 0; g4 < 4; ++g4)
#pragma unroll
            for (int r = 0; r < 4; ++r)
                wsV[b * CRF_K + 16 * g4 + 4 * q + r] = v[g4 * 4 + r] * sf;
    }
}

__global__ __launch_bounds__(256) void crf_finish(
    const float* __restrict__ ws, const float* __restrict__ sink,
    float* __restrict__ out)
{
    const int b = threadIdx.x;
    const float* wsC = ws;
    const float* wsV = ws + CRF_B * NSEG;
    const float* wsG = wsV + CRF_B * CRF_K;

    float cs = 0.f;
#pragma unroll
    for (int s = 0; s < NSEG; ++s) cs += wsC[b * NSEG + s];
    float dot = 0.f;
#pragma unroll 8
    for (int j = 0; j < CRF_K; ++j) dot += wsV[b * CRF_K + j] * __expf(sink[j]);
    float loss = cs + logf(dot) - wsG[b];

    __shared__ float red[256];
    red[b] = loss;
    __syncthreads();
    for (int s2 = 128; s2 > 0; s2 >>= 1) {
        if (b < s2) red[b] += red[b + s2];
        __syncthreads();
    }
    if (b == 0) out[0] = red[0] * (1.0f / CRF_B);
}

extern "C" void kernel_launch(void* const* d_in, const int* in_sizes, int n_in,
                              void* d_out, int out_size, void* d_ws, size_t ws_size,
                              hipStream_t stream) {
    const float* scores = (const float*)d_in[0];
    const int*   states = (const int*)d_in[1];
    const float* trans  = (const float*)d_in[2];
    const float* source = (const float*)d_in[3];
    const float* sink   = (const float*)d_in[4];

    float* ws = (float*)d_ws;
    float* out = (float*)d_out;

    crf_scan<<<CRF_B, 64, 0, stream>>>(scores, states, trans, source, sink, ws);
    crf_finish<<<1, 256, 0, stream>>>(ws, sink, out);
}

// Round 4
// 228.525 us; speedup vs baseline: 2.6114x; 1.2293x over previous
//
#include <hip/hip_runtime.h>
#include <math.h>

#define CRF_B 256
#define CRF_S 2048
#define CRF_K 64
#define NSEG 64
#define BURN 32
#define DEPTH 64  // BURN + 32 accumulation steps

typedef short bf16x8 __attribute__((ext_vector_type(8)));  // 8 bf16 = 4 VGPRs
typedef float f32x4 __attribute__((ext_vector_type(4)));

// ws layout (floats): cseg[B][NSEG], vlast[B][K], gold4[B][4]

// Compiler-only fence; per-wave DS ops are processed in-order by the LDS pipe
// (write->read visibility verified rounds 1-3, absmax 0). Waves touch disjoint
// LDS regions, so no __syncthreads needed anywhere in the scan.
__device__ __forceinline__ void lds_fence() { asm volatile("" ::: "memory"); }

__device__ __forceinline__ unsigned bf16rne(float x) {
    unsigned u = __float_as_uint(x);
    return (u + 0x7FFFu + ((u >> 16) & 1u)) >> 16;
}
// Pack trunc-bf16(x) into low half, trunc-bf16(y) into high half: 1 v_perm_b32.
__device__ __forceinline__ unsigned pktrunc(float x, float y) {
    return __builtin_amdgcn_perm(__float_as_uint(y), __float_as_uint(x), 0x07060302u);
}
__device__ __forceinline__ int expOf(float m) {  // e such that m*2^-e in [0.5,1)
    return ((__float_as_int(m) >> 23) & 255) - 126;
}

// Block = batch b, 4 waves; wave w owns chains/segments s = 16w+c (c = lane&15).
// Chain s: steps k=0..63 apply matrix step t = s*32 - 32 + k (clamped; burn-in
// k<32 re-derives the direction from uniform, accumulation k>=32 covers
// t in [s*32, s*32+31]); chain 0 gets its exact alpha_0 injected at k=32
// (its computed t=0 "step" is discarded). Max t = 63*32+31 = 2047: no step
// past the end, no freeze logic.
// MFMA (verified round 3): D[state][chain] = sum_i E[i][state]*P[chain][i];
// A[m=lane&15][k=q*8+j] static E-fragments, B = P via LDS, C col=lane&15 (chain),
// row(state-in-group) = q*4+reg.
__global__ __launch_bounds__(256, 1) void crf_scan(
    const float* __restrict__ scores, const int* __restrict__ states,
    const float* __restrict__ trans, const float* __restrict__ source,
    const float* __restrict__ sink, float* __restrict__ ws)
{
    const int tid = threadIdx.x;
    const int lane = tid & 63;
    const int w = tid >> 6;
    const int b = blockIdx.x;
    const int c = lane & 15;  // chain-within-wave
    const int q = lane >> 4;  // quad
    const int s = w * 16 + c; // global segment id 0..63

    float* wsC = ws;                     // [B][NSEG]
    float* wsV = ws + CRF_B * NSEG;      // [B][K]
    float* wsG = wsV + CRF_B * CRF_K;    // [B][4]

    __shared__ __align__(16) short Pbuf[4][16 * 72];  // per-wave [chain][state], stride 72
    short* myP = Pbuf[w];

    const float* scb = scores + (size_t)b * CRF_S * CRF_K;

    // ---------- gold-path partial (this wave's quarter of the sequence) ----------
    {
        const int* st = states + b * CRF_S;
        float g = 0.f;
#pragma unroll
        for (int it = 0; it < 8; ++it) {
            int p = w * 512 + it * 64 + lane;
            int cur = st[p];
            g += scb[(size_t)p * CRF_K + cur];
            if (p > 0) g += trans[st[p - 1] * CRF_K + cur];
            if (p == 0) g += source[cur];
            if (p == CRF_S - 1) g += sink[cur];
        }
#pragma unroll
        for (int m = 32; m >= 1; m >>= 1) g += __shfl_xor(g, m, 64);
        if (lane == 0) wsG[b * 4 + w] = g;
    }

    // ---------- static E fragments (A operand), bf16 RNE ----------
    bf16x8 Af[4][2];
#pragma unroll
    for (int g4 = 0; g4 < 4; ++g4)
#pragma unroll
        for (int h = 0; h < 2; ++h) {
            bf16x8 t;
#pragma unroll
            for (int jv = 0; jv < 8; ++jv)
                t[jv] = (short)bf16rne(__expf(trans[(h * 32 + q * 8 + jv) * CRF_K + g4 * 16 + c]));
            Af[g4][h] = t;
        }

    // exact init for chain 0: exp(source + scores[b][0][:]) (lane layout by q only)
    float ini[16];
#pragma unroll
    for (int i = 0; i < 16; ++i) {
        int st8 = 16 * (i >> 2) + 4 * q + (i & 3);
        ini[i] = __expf(source[st8] + scb[st8]);
    }

    // P init: ones (bf16 1.0 = 0x3F80)
#pragma unroll
    for (int g4 = 0; g4 < 4; ++g4)
        *(int2*)(myP + c * 72 + 16 * g4 + 4 * q) =
            make_int2((int)0x3F803F80u, (int)0x3F803F80u);
    lds_fence();
    bf16x8 bf0 = *(const bf16x8*)(myP + c * 72 + q * 8);
    bf16x8 bf1 = *(const bf16x8*)(myP + c * 72 + 32 + q * 8);

    // emission prefetch pipeline (distance 4), float4 loads
    float4 raw4[4][4];  // [slot][g4]
    const float* scq = scb + 4 * q;
    auto ld4 = [&](int k) {
        int t = s * 32 - 32 + k;
        t = min(max(t, 0), CRF_S - 1);
        const float* pr = scq + (size_t)t * CRF_K;
        const int sl = k & 3;
#pragma unroll
        for (int g4 = 0; g4 < 4; ++g4)
            raw4[sl][g4] = *(const float4*)(pr + 16 * g4);
    };
#pragma unroll
    for (int k = 0; k < 4; ++k) ld4(k);

    float v[16];
    int cint = 0, e_pend = 0;

    for (int kk = 0; kk < DEPTH; kk += 4) {
#pragma unroll
        for (int ph = 0; ph < 4; ++ph) {
            const int k = kk + ph;
            // (1) emissions for this step
            float es[16];
#pragma unroll
            for (int g4 = 0; g4 < 4; ++g4) {
                const float4 r4 = raw4[ph][g4];
                es[g4 * 4 + 0] = __expf(r4.x);
                es[g4 * 4 + 1] = __expf(r4.y);
                es[g4 * 4 + 2] = __expf(r4.z);
                es[g4 * 4 + 3] = __expf(r4.w);
            }
            // (2) MFMA: D[state][chain]
            f32x4 acc[4];
#pragma unroll
            for (int g4 = 0; g4 < 4; ++g4) {
                f32x4 z = {0.f, 0.f, 0.f, 0.f};
                z = __builtin_amdgcn_mfma_f32_16x16x32_bf16(Af[g4][0], bf0, z, 0, 0, 0);
                z = __builtin_amdgcn_mfma_f32_16x16x32_bf16(Af[g4][1], bf1, z, 0, 0, 0);
                acc[g4] = z;
            }
            // (3) v = acc*es, applying the pending strip on period boundaries
            if (ph == 0) {
                const float s2 = ldexpf(1.0f, -e_pend);
                cint += e_pend;
#pragma unroll
                for (int i = 0; i < 16; ++i) v[i] = acc[i >> 2][i & 3] * es[i] * s2;
            } else {
#pragma unroll
                for (int i = 0; i < 16; ++i) v[i] = acc[i >> 2][i & 3] * es[i];
            }
            // (4a) end-of-burn canonical strip (all chains), reset bookkeeping
            if (k == BURN - 1) {
                float mc = v[0];
#pragma unroll
                for (int i = 1; i < 16; ++i) mc = fmaxf(mc, v[i]);
                mc = fmaxf(mc, __shfl_xor(mc, 16, 64));
                mc = fmaxf(mc, __shfl_xor(mc, 32, 64));
                const float sc2 = ldexpf(1.0f, -expOf(mc));
#pragma unroll
                for (int i = 0; i < 16; ++i) v[i] *= sc2;
                cint = 0;
                e_pend = 0;
            }
            // (4b) chain-0 exact injection (its t=0 "step" result is discarded)
            if (k == BURN) {
                if (s == 0) {
#pragma unroll
                    for (int i = 0; i < 16; ++i) v[i] = ini[i];
                }
                float mc = v[0];
#pragma unroll
                for (int i = 1; i < 16; ++i) mc = fmaxf(mc, v[i]);
                mc = fmaxf(mc, __shfl_xor(mc, 16, 64));
                mc = fmaxf(mc, __shfl_xor(mc, 32, 64));
                const int ec = expOf(mc);
                if (s == 0) {
                    const float sc2 = ldexpf(1.0f, -ec);
#pragma unroll
                    for (int i = 0; i < 16; ++i) v[i] *= sc2;
                    cint = ec;
                }
            }
            // (5) periodic strip compute (stale-by-1-step; applied at next ph==0)
            if (ph == 3 && k != BURN - 1) {
                float mx = v[0];
#pragma unroll
                for (int i = 1; i < 16; ++i) mx = fmaxf(mx, v[i]);
                mx = fmaxf(mx, __shfl_xor(mx, 16, 64));
                mx = fmaxf(mx, __shfl_xor(mx, 32, 64));
                e_pend = expOf(mx);
            }
            // (6) pack (trunc) + write own chain's 16 states; read next B frags
#pragma unroll
            for (int g4 = 0; g4 < 4; ++g4) {
                unsigned lo = pktrunc(v[g4 * 4 + 0], v[g4 * 4 + 1]);
                unsigned hi = pktrunc(v[g4 * 4 + 2], v[g4 * 4 + 3]);
                *(int2*)(myP + c * 72 + 16 * g4 + 4 * q) = make_int2((int)lo, (int)hi);
            }
            lds_fence();
            bf0 = *(const bf16x8*)(myP + c * 72 + q * 8);
            bf1 = *(const bf16x8*)(myP + c * 72 + 32 + q * 8);
            // (7) prefetch emissions for step k+4 (clamped; harmless overrun)
            ld4(k + 4);
        }
    }

    // final canonical strip (telescopes with next segment's burn-in canonical)
    float mf = v[0];
#pragma unroll
    for (int i = 1; i < 16; ++i) mf = fmaxf(mf, v[i]);
    mf = fmaxf(mf, __shfl_xor(mf, 16, 64));
    mf = fmaxf(mf, __shfl_xor(mf, 32, 64));
    const int ef = expOf(mf);
    cint += ef;
    const float sf = ldexpf(1.0f, -ef);

    if (q == 0) wsC[b * NSEG + s] = (float)cint * 0.6931471805599453f;
    if (s == NSEG - 1) {
#pragma unroll
        for (int i = 0; i < 16; ++i)
            wsV[b * CRF_K + 16 * (i >> 2) + 4 * q + (i & 3)] = v[i] * sf;
    }
}

__global__ __launch_bounds__(256) void crf_finish(
    const float* __restrict__ ws, const float* __restrict__ sink,
    float* __restrict__ out)
{
    const int b = threadIdx.x;
    const float* wsC = ws;
    const float* wsV = ws + CRF_B * NSEG;
    const float* wsG = wsV + CRF_B * CRF_K;

    __shared__ float esink[CRF_K];
    if (b < CRF_K) esink[b] = __expf(sink[b]);
    __syncthreads();

    float cs = 0.f;
#pragma unroll 8
    for (int s = 0; s < NSEG; ++s) cs += wsC[b * NSEG + s];
    float dot = 0.f;
#pragma unroll 8
    for (int j = 0; j < CRF_K; ++j) dot += wsV[b * CRF_K + j] * esink[j];
    float gold = wsG[b * 4 + 0] + wsG[b * 4 + 1] + wsG[b * 4 + 2] + wsG[b * 4 + 3];
    float loss = cs + logf(dot) - gold;

    __shared__ float red[256];
    red[b] = loss;
    __syncthreads();
    for (int s2 = 128; s2 > 0; s2 >>= 1) {
        if (b < s2) red[b] += red[b + s2];
        __syncthreads();
    }
    if (b == 0) out[0] = red[0] * (1.0f / CRF_B);
}

extern "C" void kernel_launch(void* const* d_in, const int* in_sizes, int n_in,
                              void* d_out, int out_size, void* d_ws, size_t ws_size,
                              hipStream_t stream) {
    const float* scores = (const float*)d_in[0];
    const int*   states = (const int*)d_in[1];
    const float* trans  = (const float*)d_in[2];
    const float* source = (const float*)d_in[3];
    const float* sink   = (const float*)d_in[4];

    float* ws = (float*)d_ws;
    float* out = (float*)d_out;

    crf_scan<<<CRF_B, 256, 0, stream>>>(scores, states, trans, source, sink, ws);
    crf_finish<<<1, 256, 0, stream>>>(ws, sink, out);
}

// Round 5
// 221.039 us; speedup vs baseline: 2.6999x; 1.0339x over previous
//
#include <hip/hip_runtime.h>
#include <math.h>

#define CRF_B 256
#define CRF_S 2048
#define CRF_K 64
#define NSEG 128
#define SEGL 16
#define BURN 16
#define DEPTH 32  // BURN + 16 accumulation steps

typedef short bf16x8 __attribute__((ext_vector_type(8)));  // 8 bf16 = 4 VGPRs
typedef float f32x4 __attribute__((ext_vector_type(4)));

// Compiler-only fence; per-wave DS ops are processed in-order by the LDS pipe
// (write->read visibility verified rounds 1-4, absmax 0). Waves touch disjoint
// LDS regions during the scan, so no __syncthreads until the fused epilogue.
__device__ __forceinline__ void lds_fence() { asm volatile("" ::: "memory"); }

__device__ __forceinline__ unsigned bf16rne(float x) {
    unsigned u = __float_as_uint(x);
    return (u + 0x7FFFu + ((u >> 16) & 1u)) >> 16;
}
// trunc-bf16 pack of (x,y) via one v_perm_b32 (validated round 4, absmax 0).
__device__ __forceinline__ unsigned pktrunc(float x, float y) {
    return __builtin_amdgcn_perm(__float_as_uint(y), __float_as_uint(x), 0x07060302u);
}
__device__ __forceinline__ int expOf(float m) {  // e such that m*2^-e in [0.5,1)
    return ((__float_as_int(m) >> 23) & 255) - 126;
}

// Block = batch b, 8 waves (512 thr); wave w owns chains s = 16w+c (c=lane&15).
// Chain s: steps k=0..31 apply matrix step t = s*16-16+k (clamped to >=0);
// k<16 burn-in re-derives the direction from uniform, k>=16 accumulates
// t in [s*16, s*16+15]. Chain 0 gets exact alpha_0 injected at k=16 (its
// computed t=0 "step" is discarded). Max t = 127*16+15 = 2047.
// MFMA (verified r3/r4): D[state][chain] = sum_i E[i][state]*P[chain][i];
// A[m=lane&15][k=q*8+j] static E-frags, B = P via LDS, C col=lane&15 (chain),
// row(state-in-group) = q*4+reg.
__global__ __launch_bounds__(512, 2) void crf_scan(
    const float* __restrict__ scores, const int* __restrict__ states,
    const float* __restrict__ trans, const float* __restrict__ source,
    const float* __restrict__ sink, float* __restrict__ lossOut)
{
    const int tid = threadIdx.x;
    const int lane = tid & 63;
    const int w = tid >> 6;   // wave 0..7
    const int b = blockIdx.x;
    const int c = lane & 15;  // chain-within-wave
    const int q = lane >> 4;  // quad
    const int s = w * 16 + c; // global segment id 0..127

    __shared__ __align__(16) short Pbuf[8][16 * 72];  // per-wave [chain][state], stride 72
    __shared__ float sC[NSEG];
    __shared__ float gW[8];
    __shared__ float dotSh;
    short* myP = Pbuf[w];

    const float* scb = scores + (size_t)b * CRF_S * CRF_K;

    // ---------- gold-path partial (this wave's 1/8 of the sequence) ----------
    {
        const int* st = states + b * CRF_S;
        float g = 0.f;
#pragma unroll
        for (int it = 0; it < 4; ++it) {
            int p = w * 256 + it * 64 + lane;
            int cur = st[p];
            g += scb[(size_t)p * CRF_K + cur];
            if (p > 0) g += trans[st[p - 1] * CRF_K + cur];
            if (p == 0) g += source[cur];
            if (p == CRF_S - 1) g += sink[cur];
        }
#pragma unroll
        for (int m = 32; m >= 1; m >>= 1) g += __shfl_xor(g, m, 64);
        if (lane == 0) gW[w] = g;
    }

    // ---------- static E fragments (A operand), bf16 RNE ----------
    bf16x8 Af[4][2];
#pragma unroll
    for (int g4 = 0; g4 < 4; ++g4)
#pragma unroll
        for (int h = 0; h < 2; ++h) {
            bf16x8 t;
#pragma unroll
            for (int jv = 0; jv < 8; ++jv)
                t[jv] = (short)bf16rne(__expf(trans[(h * 32 + q * 8 + jv) * CRF_K + g4 * 16 + c]));
            Af[g4][h] = t;
        }

    // exact init for chain 0: exp(source + scores[b][0][:]) (layout depends on q only)
    float ini[16];
#pragma unroll
    for (int i = 0; i < 16; ++i) {
        int st8 = 16 * (i >> 2) + 4 * q + (i & 3);
        ini[i] = __expf(source[st8] + scb[st8]);
    }

    // P init: ones (bf16 1.0 = 0x3F80)
#pragma unroll
    for (int g4 = 0; g4 < 4; ++g4)
        *(int2*)(myP + c * 72 + 16 * g4 + 4 * q) =
            make_int2((int)0x3F803F80u, (int)0x3F803F80u);
    lds_fence();
    bf16x8 bf0 = *(const bf16x8*)(myP + c * 72 + q * 8);
    bf16x8 bf1 = *(const bf16x8*)(myP + c * 72 + 32 + q * 8);

    // emission prefetch pipeline (distance 4), float4 loads
    float4 raw4[4][4];  // [slot][g4]
    const float* scq = scb + 4 * q;
    auto ld4 = [&](int k) {
        int t = s * SEGL - BURN + k;
        t = min(max(t, 0), CRF_S - 1);
        const float* pr = scq + (size_t)t * CRF_K;
        const int sl = k & 3;
#pragma unroll
        for (int g4 = 0; g4 < 4; ++g4)
            raw4[sl][g4] = *(const float4*)(pr + 16 * g4);
    };
#pragma unroll
    for (int k = 0; k < 4; ++k) ld4(k);

    float v[16];
    int cint = 0, e_pend = 0;

    for (int kk = 0; kk < DEPTH; kk += 4) {
#pragma unroll
        for (int ph = 0; ph < 4; ++ph) {
            const int k = kk + ph;
            // (1) emissions for this step
            float es[16];
#pragma unroll
            for (int g4 = 0; g4 < 4; ++g4) {
                const float4 r4 = raw4[ph][g4];
                es[g4 * 4 + 0] = __expf(r4.x);
                es[g4 * 4 + 1] = __expf(r4.y);
                es[g4 * 4 + 2] = __expf(r4.z);
                es[g4 * 4 + 3] = __expf(r4.w);
            }
            // (2) MFMA: D[state][chain]
            f32x4 acc[4];
#pragma unroll
            for (int g4 = 0; g4 < 4; ++g4) {
                f32x4 z = {0.f, 0.f, 0.f, 0.f};
                z = __builtin_amdgcn_mfma_f32_16x16x32_bf16(Af[g4][0], bf0, z, 0, 0, 0);
                z = __builtin_amdgcn_mfma_f32_16x16x32_bf16(Af[g4][1], bf1, z, 0, 0, 0);
                acc[g4] = z;
            }
            // (3) v = acc*es, applying the pending strip on period boundaries
            if (ph == 0) {
                const float s2 = ldexpf(1.0f, -e_pend);
                cint += e_pend;
#pragma unroll
                for (int i = 0; i < 16; ++i) v[i] = acc[i >> 2][i & 3] * es[i] * s2;
            } else {
#pragma unroll
                for (int i = 0; i < 16; ++i) v[i] = acc[i >> 2][i & 3] * es[i];
            }
            // (4a) end-of-burn canonical strip (all chains), reset bookkeeping
            if (k == BURN - 1) {
                float mc = v[0];
#pragma unroll
                for (int i = 1; i < 16; ++i) mc = fmaxf(mc, v[i]);
                mc = fmaxf(mc, __shfl_xor(mc, 16, 64));
                mc = fmaxf(mc, __shfl_xor(mc, 32, 64));
                const float sc2 = ldexpf(1.0f, -expOf(mc));
#pragma unroll
                for (int i = 0; i < 16; ++i) v[i] *= sc2;
                cint = 0;
                e_pend = 0;
            }
            // (4b) chain-0 exact injection (its t=0 "step" result is discarded)
            if (k == BURN) {
                if (s == 0) {
#pragma unroll
                    for (int i = 0; i < 16; ++i) v[i] = ini[i];
                }
                float mc = v[0];
#pragma unroll
                for (int i = 1; i < 16; ++i) mc = fmaxf(mc, v[i]);
                mc = fmaxf(mc, __shfl_xor(mc, 16, 64));
                mc = fmaxf(mc, __shfl_xor(mc, 32, 64));
                const int ec = expOf(mc);
                if (s == 0) {
                    const float sc2 = ldexpf(1.0f, -ec);
#pragma unroll
                    for (int i = 0; i < 16; ++i) v[i] *= sc2;
                    cint = ec;
                }
            }
            // (5) periodic strip compute (stale-by-1-step; applied at next ph==0)
            if (ph == 3 && k != BURN - 1) {
                float mx = v[0];
#pragma unroll
                for (int i = 1; i < 16; ++i) mx = fmaxf(mx, v[i]);
                mx = fmaxf(mx, __shfl_xor(mx, 16, 64));
                mx = fmaxf(mx, __shfl_xor(mx, 32, 64));
                e_pend = expOf(mx);
            }
            // (6) pack (trunc) + write own chain's 16 states; read next B frags
#pragma unroll
            for (int g4 = 0; g4 < 4; ++g4) {
                unsigned lo = pktrunc(v[g4 * 4 + 0], v[g4 * 4 + 1]);
                unsigned hi = pktrunc(v[g4 * 4 + 2], v[g4 * 4 + 3]);
                *(int2*)(myP + c * 72 + 16 * g4 + 4 * q) = make_int2((int)lo, (int)hi);
            }
            lds_fence();
            bf0 = *(const bf16x8*)(myP + c * 72 + q * 8);
            bf1 = *(const bf16x8*)(myP + c * 72 + 32 + q * 8);
            // (7) prefetch emissions for step k+4 (clamped; harmless overrun)
            ld4(k + 4);
        }
    }

    // final canonical strip (telescopes with next segment's burn-in canonical)
    float mf = v[0];
#pragma unroll
    for (int i = 1; i < 16; ++i) mf = fmaxf(mf, v[i]);
    mf = fmaxf(mf, __shfl_xor(mf, 16, 64));
    mf = fmaxf(mf, __shfl_xor(mf, 32, 64));
    const int ef = expOf(mf);
    cint += ef;
    const float sf = ldexpf(1.0f, -ef);

    // ---------- fused per-batch epilogue ----------
    if (q == 0) sC[s] = (float)cint * 0.6931471805599453f;
    if (w == 7) {
        // chain 127 lanes: dot(vlast, exp(sink))
        float pd = 0.f;
        if (c == 15) {
#pragma unroll
            for (int i = 0; i < 16; ++i) {
                int st8 = 16 * (i >> 2) + 4 * q + (i & 3);
                pd += v[i] * sf * __expf(sink[st8]);
            }
        }
        pd += __shfl_xor(pd, 16, 64);
        pd += __shfl_xor(pd, 32, 64);
        if (lane == 15) dotSh = pd;
    }
    __syncthreads();
    if (w == 0) {
        float t2 = sC[lane] + sC[lane + 64];
#pragma unroll
        for (int m = 32; m >= 1; m >>= 1) t2 += __shfl_xor(t2, m, 64);
        if (lane == 0) {
            float gold = 0.f;
#pragma unroll
            for (int i = 0; i < 8; ++i) gold += gW[i];
            lossOut[b] = t2 + logf(dotSh) - gold;
        }
    }
}

__global__ __launch_bounds__(256) void crf_finish(
    const float* __restrict__ loss, float* __restrict__ out)
{
    const int b = threadIdx.x;
    __shared__ float red[256];
    red[b] = loss[b];
    __syncthreads();
    for (int s2 = 128; s2 > 0; s2 >>= 1) {
        if (b < s2) red[b] += red[b + s2];
        __syncthreads();
    }
    if (b == 0) out[0] = red[0] * (1.0f / CRF_B);
}

extern "C" void kernel_launch(void* const* d_in, const int* in_sizes, int n_in,
                              void* d_out, int out_size, void* d_ws, size_t ws_size,
                              hipStream_t stream) {
    const float* scores = (const float*)d_in[0];
    const int*   states = (const int*)d_in[1];
    const float* trans  = (const float*)d_in[2];
    const float* source = (const float*)d_in[3];
    const float* sink   = (const float*)d_in[4];

    float* loss = (float*)d_ws;
    float* out = (float*)d_out;

    crf_scan<<<CRF_B, 512, 0, stream>>>(scores, states, trans, source, sink, loss);
    crf_finish<<<1, 256, 0, stream>>>(loss, out);
}